// Round 7
// baseline (725.763 us; speedup 1.0000x reference)
//
#include <hip/hip_runtime.h>
#include <math.h>

// EulerAttention: B=2, S=4096, D=1024.
// Pipeline: [K0] split fp32 -> (hi,lo) bf16 for x and stacked W  (elementwise)
//           [K1] split-bf16 MFMA GEMM (3-term: hh + hl + lh), M=8192 N=3072 K=1024,
//                epilogue: bias + HW-trig sincos -> Qf/Kf bf16 features, V -> Vt bf16
//           per batch b:
//           [K2] bf16 MFMA NT GEMM: sim(fp32) = Qf @ Kf^T  (K=2048)
//           [K3] row softmax: fp32 sim -> bf16 P in place (row stride 8192)
//           [K4] bf16 MFMA NT GEMM split-K x4 + fp32 atomics: out += P @ Vt^T
// ws: [sim 67MB fp32 (aliases Xhi|Xlo|Whi|Wlo 46MB used only before K2)]
//     [Qf 33.5MB][Kf 33.5MB][Vt 16.8MB]  = ~151MB
//
// Precision notes (load-bearing):
//  - sim ~ 640 +- ~15 (cos(small)~1 common mode). sim MUST be fp32 (R1 failure).
//  - Q/K need near-fp32: inv_wl[0]~163 amplifies Q error. 3-term split-bf16.
//  - R3 failure: libm sincosf + reg pressure -> scratch spill -> 3.2GB phantom
//    writes. Trig MUST be inline v_sin/v_cos (revolutions, fract-reduced).
// Perf notes:
//  - R4: proj at 827 TF (m97-structure plateau). Leave alone.
//  - R5/R6 post-mortem: unpadded stride-32 LDS (required by global_load_lds)
//    gives 8-WAY bank conflicts on fragment ds_read_b128 (bank = 16(row&1)+4q:
//    16 lanes -> 2 banks). ~56% of K2/K4 cycles were LDS serialization; that's
//    why DMA staging (R5) and split-K occupancy (R6) were both neutral.
//  - R7: XOR-swizzled DMA landing: lane i fetches global chunk (i&3)^((i>>3)&3)
//    so fragment (row,q) sits at slot row*4+(q^((row>>1)&3)) -> every bank
//    exactly 2-way across a quad = free (m136). Staging stays full-width DMA.

typedef __attribute__((ext_vector_type(8))) short bf16x8;
typedef __attribute__((ext_vector_type(4))) float f32x4;

__device__ __forceinline__ float b2f(unsigned short h) {
    union { unsigned int u; float f; } v; v.u = ((unsigned int)h) << 16; return v.f;
}
__device__ __forceinline__ unsigned short f2b(float f) {
    union { float f; unsigned int u; } v; v.f = f;
    unsigned int r = v.u + 0x7fffu + ((v.u >> 16) & 1u);
    return (unsigned short)(r >> 16);
}

// Async global->LDS 16B per lane. LDS dest = wave-uniform base + lane*16.
__device__ __forceinline__ void async_load16(const unsigned short* g, unsigned short* l) {
    __builtin_amdgcn_global_load_lds(
        (const __attribute__((address_space(1))) unsigned int*)g,
        (__attribute__((address_space(3))) unsigned int*)l, 16, 0, 0);
}

// Branch-free sin/cos of th (radians). HW v_sin/v_cos take REVOLUTIONS:
// D = sin(S0 * 2pi); reduce to [0,1) via floor.
__device__ __forceinline__ void fast_sincos(float th, float* sn, float* cs) {
    float rev = th * 0.15915494309189535f;   // th / (2*pi)
    float fr  = rev - floorf(rev);           // [0,1)
    float s, c;
    asm("v_sin_f32 %0, %1" : "=v"(s) : "v"(fr));
    asm("v_cos_f32 %0, %1" : "=v"(c) : "v"(fr));
    *sn = s; *cs = c;
}

// ---------------- K0: fp32 -> (hi, lo) bf16 split ----------------
__global__ __launch_bounds__(256) void split_kernel(
    const float* __restrict__ src,
    unsigned short* __restrict__ hi, unsigned short* __restrict__ lo, int n4)
{
    int i = blockIdx.x * 256 + threadIdx.x;
    if (i >= n4) return;
    float4 v = ((const float4*)src)[i];
    float f[4] = { v.x, v.y, v.z, v.w };
    unsigned short h[4], l[4];
#pragma unroll
    for (int j = 0; j < 4; j++) {
        h[j] = f2b(f[j]);
        float r = f[j] - b2f(h[j]);
        l[j] = f2b(r);
    }
    uint2 ho, lv;
    ho.x = (unsigned int)h[0] | ((unsigned int)h[1] << 16);
    ho.y = (unsigned int)h[2] | ((unsigned int)h[3] << 16);
    lv.x = (unsigned int)l[0] | ((unsigned int)l[1] << 16);
    lv.y = (unsigned int)l[2] | ((unsigned int)l[3] << 16);
    ((uint2*)hi)[i] = ho;
    ((uint2*)lo)[i] = lv;
}

// W splits fused: grid.y picks Wq/Wk/Wv -> stacked hi/lo at y*1024*1024.
__global__ __launch_bounds__(256) void split_w_kernel(
    const float* __restrict__ Wq, const float* __restrict__ Wk,
    const float* __restrict__ Wv,
    unsigned short* __restrict__ hi, unsigned short* __restrict__ lo)
{
    const int y = blockIdx.y;
    const float* src = (y == 0) ? Wq : ((y == 1) ? Wk : Wv);
    size_t off4 = (size_t)y * (1024 * 1024 / 4);
    int i = blockIdx.x * 256 + threadIdx.x;   // < 1024*1024/4
    float4 v = ((const float4*)src)[i];
    float f[4] = { v.x, v.y, v.z, v.w };
    unsigned short h[4], l[4];
#pragma unroll
    for (int j = 0; j < 4; j++) {
        h[j] = f2b(f[j]);
        float r = f[j] - b2f(h[j]);
        l[j] = f2b(r);
    }
    uint2 ho, lv;
    ho.x = (unsigned int)h[0] | ((unsigned int)h[1] << 16);
    ho.y = (unsigned int)h[2] | ((unsigned int)h[3] << 16);
    lv.x = (unsigned int)l[0] | ((unsigned int)l[1] << 16);
    lv.y = (unsigned int)l[2] | ((unsigned int)l[3] << 16);
    ((uint2*)hi)[off4 + i] = ho;
    ((uint2*)lo)[off4 + i] = lv;
}

// ---------------- K1: split-bf16 MFMA projection GEMM ----------------
// C = X@W^T via 3-term split; grid (24, 64): n0 = bx*128 in [0,3072), m0 = by*128.
// n-blocks 0-7 -> Q, 8-15 -> K, 16-23 -> V (z = n0>>10, uniform per block).
__global__ __launch_bounds__(256, 2) void proj_kernel(
    const unsigned short* __restrict__ Xhi, const unsigned short* __restrict__ Xlo,
    const unsigned short* __restrict__ Whi, const unsigned short* __restrict__ Wlo,
    const float* __restrict__ bq, const float* __restrict__ bk,
    const float* __restrict__ bv, const float* __restrict__ phase,
    unsigned short* __restrict__ Qf, unsigned short* __restrict__ Kf,
    unsigned short* __restrict__ Vt)
{
    const int m0 = blockIdx.y * 128;
    const int n0 = blockIdx.x * 128;

    __shared__ unsigned short Ah[128 * 40], Al[128 * 40];
    __shared__ unsigned short Bh[128 * 40], Bl[128 * 40];

    const int tid  = threadIdx.x;
    const int lane = tid & 63;
    const int w    = tid >> 6;
    const int wr   = w >> 1, wc = w & 1;
    const int l15  = lane & 15, q = lane >> 4;

    f32x4 acc[4][4];
#pragma unroll
    for (int a = 0; a < 4; a++)
#pragma unroll
        for (int b = 0; b < 4; b++) acc[a][b] = (f32x4){0.f, 0.f, 0.f, 0.f};

    for (int k0 = 0; k0 < 1024; k0 += 32) {
#pragma unroll
        for (int i = 0; i < 2; i++) {
            int idx = tid + 256 * i;
            int row = idx >> 2;
            int cc  = idx & 3;
            size_t ga = (size_t)(m0 + row) * 1024 + k0 + cc * 8;
            size_t gb = (size_t)(n0 + row) * 1024 + k0 + cc * 8;
            *(uint4*)&Ah[row * 40 + cc * 8] = *(const uint4*)&Xhi[ga];
            *(uint4*)&Al[row * 40 + cc * 8] = *(const uint4*)&Xlo[ga];
            *(uint4*)&Bh[row * 40 + cc * 8] = *(const uint4*)&Whi[gb];
            *(uint4*)&Bl[row * 40 + cc * 8] = *(const uint4*)&Wlo[gb];
        }
        __syncthreads();
        bf16x8 ah[4], al[4];
#pragma unroll
        for (int mt = 0; mt < 4; mt++) {
            int off = (wr * 64 + mt * 16 + l15) * 40 + q * 8;
            ah[mt] = *(const bf16x8*)&Ah[off];
            al[mt] = *(const bf16x8*)&Al[off];
        }
#pragma unroll
        for (int nt = 0; nt < 4; nt++) {
            int off = (wc * 64 + nt * 16 + l15) * 40 + q * 8;
            bf16x8 bh = *(const bf16x8*)&Bh[off];
            bf16x8 bl = *(const bf16x8*)&Bl[off];
#pragma unroll
            for (int mt = 0; mt < 4; mt++) {
                acc[mt][nt] = __builtin_amdgcn_mfma_f32_16x16x32_bf16(
                    ah[mt], bh, acc[mt][nt], 0, 0, 0);
                acc[mt][nt] = __builtin_amdgcn_mfma_f32_16x16x32_bf16(
                    ah[mt], bl, acc[mt][nt], 0, 0, 0);
                acc[mt][nt] = __builtin_amdgcn_mfma_f32_16x16x32_bf16(
                    al[mt], bh, acc[mt][nt], 0, 0, 0);
            }
        }
        __syncthreads();
    }

    const int z = n0 >> 10;                   // 0=Q, 1=K, 2=V
    const float* bias = (z == 0) ? bq : ((z == 1) ? bk : bv);
    const float w0 = (float)(2.0 * M_PI / 1024.0);

#pragma unroll
    for (int mt = 0; mt < 4; mt++) {
#pragma unroll
        for (int nt = 0; nt < 4; nt++) {
            int n = n0 + wc * 64 + nt * 16 + l15;
            int f = n & 1023;
            float bsv = bias[f];
            float wl  = (float)(f + 1) * w0;
            float inv = 1.0f / (wl + 1e-8f);
            float phv = phase[f];
#pragma unroll
            for (int r = 0; r < 4; r++) {
                int m  = m0 + wr * 64 + mt * 16 + q * 4 + r;   // row in [0,8192)
                int bb = m >> 12;
                int s  = m & 4095;
                float val = acc[mt][nt][r] + bsv;
                if (z == 2) {
                    Vt[((size_t)bb * 1024 + f) * 4096 + s] = f2b(val);
                } else {
                    float th = fmaf(val, inv, phv);
                    float sn, cs;
                    fast_sincos(th, &sn, &cs);
                    unsigned short* dst = (z == 0) ? Qf : Kf;
                    size_t base = ((size_t)bb * 4096 + s) * 2048;
                    dst[base + f]        = f2b(cs);
                    dst[base + 1024 + f] = f2b(sn);
                }
            }
        }
    }
}

// ---------------- K2/K4: bf16 MFMA NT GEMM (swizzled DMA staging) ----------
// C[m][n] (+)= sum_{k in z-slice} A[m][k] * Bm[n][k]; 128x128 tile, BK=32,
// 4 waves (2x2), each wave 64x64 via 4x4 mfma_f32_16x16x32_bf16.
// Staging: global_load_lds width=16, XOR-swizzled landing (see header note):
//   lane i of a 16-row issue fetches global chunk (i&3)^((i>>3)&3); fragment
//   (row,q) then sits at 16B-slot row*4 + (q^((row>>1)&3)) -> ds_read_b128
//   conflicts reduced 8-way -> 2-way (free).
// blockIdx.z selects K-slice for split-K; ATOMIC=true combines via
// device-scope fp32 atomics (C pre-zeroed).
template <bool ATOMIC>
__global__ __launch_bounds__(256) void gemm_nt(
    const unsigned short* __restrict__ A,
    const unsigned short* __restrict__ Bm,
    float* __restrict__ C,
    int M, int N, int K, int lda, int ldb)
{
    const int m0 = blockIdx.y * 128;
    const int n0 = blockIdx.x * 128;
    const int koff = blockIdx.z * K;

    __shared__ unsigned short As[128 * 32];
    __shared__ unsigned short Bs[128 * 32];

    const int tid  = threadIdx.x;
    const int lane = tid & 63;
    const int w    = tid >> 6;
    const int wr   = w >> 1, wc = w & 1;
    const int l15  = lane & 15, q = lane >> 4;
    const int lrow = lane >> 2;                    // 0..15 within a 16-row issue
    const int cgl  = (lane & 3) ^ ((lane >> 3) & 3); // global chunk to fetch (swizzle)
    const int qx   = q ^ ((l15 >> 1) & 3);         // swizzled read chunk

    f32x4 acc[4][4];
#pragma unroll
    for (int a = 0; a < 4; a++)
#pragma unroll
        for (int b = 0; b < 4; b++) acc[a][b] = (f32x4){0.f, 0.f, 0.f, 0.f};

    for (int k0 = 0; k0 < K; k0 += 32) {
        int kg = koff + k0;
#pragma unroll
        for (int i = 0; i < 2; i++) {
            int chunk = w * 2 + i;       // 16-row group: rows [chunk*16, chunk*16+16)
            async_load16(&A[(size_t)(m0 + chunk * 16 + lrow) * lda + kg + cgl * 8],
                         &As[chunk * 512]);
            async_load16(&Bm[(size_t)(n0 + chunk * 16 + lrow) * ldb + kg + cgl * 8],
                         &Bs[chunk * 512]);
        }
        __syncthreads();
        bf16x8 af[4], bfr[4];
#pragma unroll
        for (int mt = 0; mt < 4; mt++) {
            int ar = wr * 64 + mt * 16 + l15;
            af[mt] = *(const bf16x8*)&As[(ar * 4 + qx) * 8];
        }
#pragma unroll
        for (int nt = 0; nt < 4; nt++) {
            int br = wc * 64 + nt * 16 + l15;
            bfr[nt] = *(const bf16x8*)&Bs[(br * 4 + qx) * 8];
        }
#pragma unroll
        for (int mt = 0; mt < 4; mt++)
#pragma unroll
            for (int nt = 0; nt < 4; nt++)
                acc[mt][nt] = __builtin_amdgcn_mfma_f32_16x16x32_bf16(
                    af[mt], bfr[nt], acc[mt][nt], 0, 0, 0);
        __syncthreads();
    }

#pragma unroll
    for (int mt = 0; mt < 4; mt++) {
#pragma unroll
        for (int nt = 0; nt < 4; nt++) {
            int n = n0 + wc * 64 + nt * 16 + l15;
#pragma unroll
            for (int r = 0; r < 4; r++) {
                int m = m0 + wr * 64 + mt * 16 + q * 4 + r;  // C/D: col=lane&15, row=quad*4+reg
                float* p = &C[(size_t)m * N + n];
                if (ATOMIC)
                    __hip_atomic_fetch_add(p, acc[mt][nt][r],
                                           __ATOMIC_RELAXED, __HIP_MEMORY_SCOPE_AGENT);
                else
                    *p = acc[mt][nt][r];
            }
        }
    }
}

// ---------------- K3: row softmax, fp32 sim -> bf16 P in place ----------------
// One block per row. Reads 4096 fp32 at sim + row*4096; writes 4096 bf16 at
// (ushort*)sim + row*8192 (same byte range start; all reads precede writes).
__global__ __launch_bounds__(256) void softmax_kernel(float* __restrict__ sim)
{
    const size_t row = blockIdx.x;
    const float* pin = sim + row * 4096;
    unsigned short* pout = (unsigned short*)sim + row * 8192;
    const int tid = threadIdx.x;

    float v[16];
#pragma unroll
    for (int i = 0; i < 4; i++) {
        float4 d = ((const float4*)pin)[tid * 4 + i];
        v[4 * i + 0] = d.x * 0.03125f;
        v[4 * i + 1] = d.y * 0.03125f;
        v[4 * i + 2] = d.z * 0.03125f;
        v[4 * i + 3] = d.w * 0.03125f;
    }

    float m = v[0];
#pragma unroll
    for (int i = 1; i < 16; i++) m = fmaxf(m, v[i]);
    for (int o = 32; o > 0; o >>= 1) m = fmaxf(m, __shfl_xor(m, o));
    __shared__ float red[4];
    if ((tid & 63) == 0) red[tid >> 6] = m;
    __syncthreads();
    m = fmaxf(fmaxf(red[0], red[1]), fmaxf(red[2], red[3]));
    __syncthreads();   // protect red[] before reuse

    float e[16];
    float s = 0.f;
#pragma unroll
    for (int i = 0; i < 16; i++) { e[i] = expf(v[i] - m); s += e[i]; }
    for (int o = 32; o > 0; o >>= 1) s += __shfl_xor(s, o);
    if ((tid & 63) == 0) red[tid >> 6] = s;
    __syncthreads();
    float l = (red[0] + red[1]) + (red[2] + red[3]);
    float inv = 1.0f / l;

#pragma unroll
    for (int c = 0; c < 2; c++) {
        unsigned int wds[4];
#pragma unroll
        for (int i = 0; i < 4; i++) {
            unsigned int lo = f2b(e[c * 8 + 2 * i] * inv);
            unsigned int hi = f2b(e[c * 8 + 2 * i + 1] * inv);
            wds[i] = lo | (hi << 16);
        }
        uint4 o4; o4.x = wds[0]; o4.y = wds[1]; o4.z = wds[2]; o4.w = wds[3];
        ((uint4*)pout)[tid * 2 + c] = o4;
    }
}

extern "C" void kernel_launch(void* const* d_in, const int* in_sizes, int n_in,
                              void* d_out, int out_size, void* d_ws, size_t ws_size,
                              hipStream_t stream)
{
    const float* x  = (const float*)d_in[0];
    const float* Wq = (const float*)d_in[1];
    const float* bq = (const float*)d_in[2];
    const float* Wk = (const float*)d_in[3];
    const float* bk = (const float*)d_in[4];
    const float* Wv = (const float*)d_in[5];
    const float* bv = (const float*)d_in[6];
    const float* ph = (const float*)d_in[7];

    char* ws = (char*)d_ws;
    // Region A (first 67.1MB): Xhi|Xlo|Whi|Wlo (46.1MB) before K2; sim fp32 after.
    unsigned short* Xhi = (unsigned short*)ws;                    // 8192*1024
    unsigned short* Xlo = Xhi + (size_t)8192 * 1024;
    unsigned short* Whi = Xlo + (size_t)8192 * 1024;              // 3072*1024 stacked
    unsigned short* Wlo = Whi + (size_t)3072 * 1024;
    float*          sim = (float*)ws;                             // 4096*4096 fp32
    // Region B:
    unsigned short* Qf = (unsigned short*)(ws + (size_t)4096 * 4096 * 4);  // [2][4096][2048]
    unsigned short* Kf = Qf + (size_t)2 * 4096 * 2048;                     // [2][4096][2048]
    unsigned short* Vt = Kf + (size_t)2 * 4096 * 2048;                     // [2][1024][4096]

    // Zero d_out for split-K atomics (re-poisoned 0xAA before each replay).
    hipMemsetAsync(d_out, 0, (size_t)2 * 4096 * 1024 * sizeof(float), stream);

    // K0: splits
    split_kernel<<<8192, 256, 0, stream>>>(x, Xhi, Xlo, 8192 * 1024 / 4);
    split_w_kernel<<<dim3(1024, 3), 256, 0, stream>>>(Wq, Wk, Wv, Whi, Wlo);

    // K1: split-bf16 MFMA projection + feature epilogue
    proj_kernel<<<dim3(24, 64), 256, 0, stream>>>(Xhi, Xlo, Whi, Wlo,
                                                  bq, bk, bv, ph, Qf, Kf, Vt);

    for (int b = 0; b < 2; b++) {
        const unsigned short* Qb = Qf + (size_t)b * 4096 * 2048;
        const unsigned short* Kb = Kf + (size_t)b * 4096 * 2048;
        const unsigned short* Vb = Vt + (size_t)b * 1024 * 4096;
        float* outb = (float*)d_out + (size_t)b * 4096 * 1024;

        // sim = Qf @ Kf^T, fp32 out
        gemm_nt<false><<<dim3(32, 32, 1), 256, 0, stream>>>(Qb, Kb, sim,
                                                            4096, 4096, 2048, 2048, 2048);
        // softmax rows, bf16 P in place (row stride 8192 shorts)
        softmax_kernel<<<4096, 256, 0, stream>>>(sim);
        // out += P @ Vt^T, split-K x4 (K=1024 per z), fp32 atomics
        gemm_nt<true><<<dim3(8, 32, 4), 256, 0, stream>>>((const unsigned short*)sim, Vb, outb,
                                                          4096, 1024, 1024, 8192, 4096);
    }
}

// Round 8
// 666.814 us; speedup vs baseline: 1.0884x; 1.0884x over previous
//
#include <hip/hip_runtime.h>
#include <math.h>

// EulerAttention: B=2, S=4096, D=1024.
// Pipeline: [K0] split fp32 -> (hi,lo) bf16 for x and stacked W  (elementwise)
//           [K1] split-bf16 MFMA GEMM (3-term), M=8192 N=3072 K=1024,
//                epilogue: bias + HW-trig sincos -> Qf/Kf bf16 features, V -> Vt
//           [K2] bf16 MFMA NT GEMM (batches merged, z=2): sim(fp32) = Qf @ Kf^T
//           [K3] row softmax: fp32 sim -> bf16 P in place (row stride 8192)
//           [K4] bf16 MFMA NT GEMM (z=8: 2 batches x 4 K-slices) + fp32 atomics
// ws (two-sim mode, 218MB): [sim0 67MB (aliases split bufs 46MB, dead after
//   proj)][Qf 33.5][Kf 33.5][Vt 16.8][sim1 67]. Fallback <218MB: sequential
//   per-batch with one sim (R7 layout).
//
// Precision notes (load-bearing):
//  - sim ~ 640 +- ~15 (cos(small)~1 common mode). sim MUST be fp32 (R1 failure).
//  - Q/K need near-fp32: inv_wl[0]~163 amplifies Q error. 3-term split-bf16.
//  - R3 failure: libm sincosf + reg pressure -> scratch spill -> 3.2GB phantom
//    writes. Trig MUST be inline v_sin/v_cos (revolutions, fract-reduced).
// Perf notes:
//  - R4: proj at 827 TF (m97-structure plateau). Leave alone.
//  - R5 (DMA staging), R6 (split-K occupancy), R7 (XOR de-conflict swizzle)
//    were ALL neutral on K2/K4 -> those were not the binding constraints.
//  - R8: (a) merge batches into single dispatches w/ distinct names so K2/K4
//    finally show in top-5 profile rows; (b) compile-time LDA/LDB/LDC/KLEN
//    (m97 hard-coded these; runtime strides were the last structural diff).

typedef __attribute__((ext_vector_type(8))) short bf16x8;
typedef __attribute__((ext_vector_type(4))) float f32x4;

__device__ __forceinline__ float b2f(unsigned short h) {
    union { unsigned int u; float f; } v; v.u = ((unsigned int)h) << 16; return v.f;
}
__device__ __forceinline__ unsigned short f2b(float f) {
    union { float f; unsigned int u; } v; v.f = f;
    unsigned int r = v.u + 0x7fffu + ((v.u >> 16) & 1u);
    return (unsigned short)(r >> 16);
}

// Async global->LDS 16B per lane. LDS dest = wave-uniform base + lane*16.
__device__ __forceinline__ void async_load16(const unsigned short* g, unsigned short* l) {
    __builtin_amdgcn_global_load_lds(
        (const __attribute__((address_space(1))) unsigned int*)g,
        (__attribute__((address_space(3))) unsigned int*)l, 16, 0, 0);
}

// Branch-free sin/cos of th (radians). HW v_sin/v_cos take REVOLUTIONS.
__device__ __forceinline__ void fast_sincos(float th, float* sn, float* cs) {
    float rev = th * 0.15915494309189535f;
    float fr  = rev - floorf(rev);
    float s, c;
    asm("v_sin_f32 %0, %1" : "=v"(s) : "v"(fr));
    asm("v_cos_f32 %0, %1" : "=v"(c) : "v"(fr));
    *sn = s; *cs = c;
}

// ---------------- K0: fp32 -> (hi, lo) bf16 split ----------------
__global__ __launch_bounds__(256) void split_kernel(
    const float* __restrict__ src,
    unsigned short* __restrict__ hi, unsigned short* __restrict__ lo, int n4)
{
    int i = blockIdx.x * 256 + threadIdx.x;
    if (i >= n4) return;
    float4 v = ((const float4*)src)[i];
    float f[4] = { v.x, v.y, v.z, v.w };
    unsigned short h[4], l[4];
#pragma unroll
    for (int j = 0; j < 4; j++) {
        h[j] = f2b(f[j]);
        float r = f[j] - b2f(h[j]);
        l[j] = f2b(r);
    }
    uint2 ho, lv;
    ho.x = (unsigned int)h[0] | ((unsigned int)h[1] << 16);
    ho.y = (unsigned int)h[2] | ((unsigned int)h[3] << 16);
    lv.x = (unsigned int)l[0] | ((unsigned int)l[1] << 16);
    lv.y = (unsigned int)l[2] | ((unsigned int)l[3] << 16);
    ((uint2*)hi)[i] = ho;
    ((uint2*)lo)[i] = lv;
}

__global__ __launch_bounds__(256) void split_w_kernel(
    const float* __restrict__ Wq, const float* __restrict__ Wk,
    const float* __restrict__ Wv,
    unsigned short* __restrict__ hi, unsigned short* __restrict__ lo)
{
    const int y = blockIdx.y;
    const float* src = (y == 0) ? Wq : ((y == 1) ? Wk : Wv);
    size_t off4 = (size_t)y * (1024 * 1024 / 4);
    int i = blockIdx.x * 256 + threadIdx.x;
    float4 v = ((const float4*)src)[i];
    float f[4] = { v.x, v.y, v.z, v.w };
    unsigned short h[4], l[4];
#pragma unroll
    for (int j = 0; j < 4; j++) {
        h[j] = f2b(f[j]);
        float r = f[j] - b2f(h[j]);
        l[j] = f2b(r);
    }
    uint2 ho, lv;
    ho.x = (unsigned int)h[0] | ((unsigned int)h[1] << 16);
    ho.y = (unsigned int)h[2] | ((unsigned int)h[3] << 16);
    lv.x = (unsigned int)l[0] | ((unsigned int)l[1] << 16);
    lv.y = (unsigned int)l[2] | ((unsigned int)l[3] << 16);
    ((uint2*)hi)[off4 + i] = ho;
    ((uint2*)lo)[off4 + i] = lv;
}

// ---------------- K1: split-bf16 MFMA projection GEMM ----------------
__global__ __launch_bounds__(256, 2) void proj_kernel(
    const unsigned short* __restrict__ Xhi, const unsigned short* __restrict__ Xlo,
    const unsigned short* __restrict__ Whi, const unsigned short* __restrict__ Wlo,
    const float* __restrict__ bq, const float* __restrict__ bk,
    const float* __restrict__ bv, const float* __restrict__ phase,
    unsigned short* __restrict__ Qf, unsigned short* __restrict__ Kf,
    unsigned short* __restrict__ Vt)
{
    const int m0 = blockIdx.y * 128;
    const int n0 = blockIdx.x * 128;

    __shared__ unsigned short Ah[128 * 40], Al[128 * 40];
    __shared__ unsigned short Bh[128 * 40], Bl[128 * 40];

    const int tid  = threadIdx.x;
    const int lane = tid & 63;
    const int w    = tid >> 6;
    const int wr   = w >> 1, wc = w & 1;
    const int l15  = lane & 15, q = lane >> 4;

    f32x4 acc[4][4];
#pragma unroll
    for (int a = 0; a < 4; a++)
#pragma unroll
        for (int b = 0; b < 4; b++) acc[a][b] = (f32x4){0.f, 0.f, 0.f, 0.f};

    for (int k0 = 0; k0 < 1024; k0 += 32) {
#pragma unroll
        for (int i = 0; i < 2; i++) {
            int idx = tid + 256 * i;
            int row = idx >> 2;
            int cc  = idx & 3;
            size_t ga = (size_t)(m0 + row) * 1024 + k0 + cc * 8;
            size_t gb = (size_t)(n0 + row) * 1024 + k0 + cc * 8;
            *(uint4*)&Ah[row * 40 + cc * 8] = *(const uint4*)&Xhi[ga];
            *(uint4*)&Al[row * 40 + cc * 8] = *(const uint4*)&Xlo[ga];
            *(uint4*)&Bh[row * 40 + cc * 8] = *(const uint4*)&Whi[gb];
            *(uint4*)&Bl[row * 40 + cc * 8] = *(const uint4*)&Wlo[gb];
        }
        __syncthreads();
        bf16x8 ah[4], al[4];
#pragma unroll
        for (int mt = 0; mt < 4; mt++) {
            int off = (wr * 64 + mt * 16 + l15) * 40 + q * 8;
            ah[mt] = *(const bf16x8*)&Ah[off];
            al[mt] = *(const bf16x8*)&Al[off];
        }
#pragma unroll
        for (int nt = 0; nt < 4; nt++) {
            int off = (wc * 64 + nt * 16 + l15) * 40 + q * 8;
            bf16x8 bh = *(const bf16x8*)&Bh[off];
            bf16x8 bl = *(const bf16x8*)&Bl[off];
#pragma unroll
            for (int mt = 0; mt < 4; mt++) {
                acc[mt][nt] = __builtin_amdgcn_mfma_f32_16x16x32_bf16(
                    ah[mt], bh, acc[mt][nt], 0, 0, 0);
                acc[mt][nt] = __builtin_amdgcn_mfma_f32_16x16x32_bf16(
                    ah[mt], bl, acc[mt][nt], 0, 0, 0);
                acc[mt][nt] = __builtin_amdgcn_mfma_f32_16x16x32_bf16(
                    al[mt], bh, acc[mt][nt], 0, 0, 0);
            }
        }
        __syncthreads();
    }

    const int z = n0 >> 10;                   // 0=Q, 1=K, 2=V
    const float* bias = (z == 0) ? bq : ((z == 1) ? bk : bv);
    const float w0 = (float)(2.0 * M_PI / 1024.0);

#pragma unroll
    for (int mt = 0; mt < 4; mt++) {
#pragma unroll
        for (int nt = 0; nt < 4; nt++) {
            int n = n0 + wc * 64 + nt * 16 + l15;
            int f = n & 1023;
            float bsv = bias[f];
            float wl  = (float)(f + 1) * w0;
            float inv = 1.0f / (wl + 1e-8f);
            float phv = phase[f];
#pragma unroll
            for (int r = 0; r < 4; r++) {
                int m  = m0 + wr * 64 + mt * 16 + q * 4 + r;
                int bb = m >> 12;
                int s  = m & 4095;
                float val = acc[mt][nt][r] + bsv;
                if (z == 2) {
                    Vt[((size_t)bb * 1024 + f) * 4096 + s] = f2b(val);
                } else {
                    float th = fmaf(val, inv, phv);
                    float sn, cs;
                    fast_sincos(th, &sn, &cs);
                    unsigned short* dst = (z == 0) ? Qf : Kf;
                    size_t base = ((size_t)bb * 4096 + s) * 2048;
                    dst[base + f]        = f2b(cs);
                    dst[base + 1024 + f] = f2b(sn);
                }
            }
        }
    }
}

// ---------------- K2/K4 core: bf16 MFMA NT GEMM, compile-time strides ------
// C[m][n] (+)= sum_{k in slice} A[m][k]*Bm[n][k]. 128x128 tile, BK=32,
// 4 waves 2x2, mfma_f32_16x16x32_bf16 4x4/wave. Swizzled global_load_lds
// (width=16): lane i fetches global chunk (i&3)^((i>>3)&3); fragment (row,q)
// at 16B-slot row*4+(q^((row>>1)&3)) -> 2-way banks (free).
// blockIdx.z = batch*SLICES + slice; slice picks K window [slice*KLEN, ...).
template <int LDA, int LDB, int LDC, int KLEN, int SLICES, bool ATOMIC>
__device__ __forceinline__ void gemm_core(
    const unsigned short* __restrict__ A,
    const unsigned short* __restrict__ Bm,
    float* __restrict__ C, size_t sA, size_t sB, size_t sC)
{
    const int bz = blockIdx.z;
    const int batch = bz / SLICES;
    const int slice = bz % SLICES;
    A  += (size_t)batch * sA;
    Bm += (size_t)batch * sB;
    C  += (size_t)batch * sC;
    const int koff = slice * KLEN;

    const int m0 = blockIdx.y * 128;
    const int n0 = blockIdx.x * 128;

    __shared__ unsigned short As[128 * 32];
    __shared__ unsigned short Bs[128 * 32];

    const int tid  = threadIdx.x;
    const int lane = tid & 63;
    const int w    = tid >> 6;
    const int wr   = w >> 1, wc = w & 1;
    const int l15  = lane & 15, q = lane >> 4;
    const int lrow = lane >> 2;
    const int cgl  = (lane & 3) ^ ((lane >> 3) & 3);
    const int qx   = q ^ ((l15 >> 1) & 3);

    f32x4 acc[4][4];
#pragma unroll
    for (int a = 0; a < 4; a++)
#pragma unroll
        for (int b = 0; b < 4; b++) acc[a][b] = (f32x4){0.f, 0.f, 0.f, 0.f};

    for (int k0 = 0; k0 < KLEN; k0 += 32) {
        int kg = koff + k0;
#pragma unroll
        for (int i = 0; i < 2; i++) {
            int chunk = w * 2 + i;
            async_load16(&A[(size_t)(m0 + chunk * 16 + lrow) * LDA + kg + cgl * 8],
                         &As[chunk * 512]);
            async_load16(&Bm[(size_t)(n0 + chunk * 16 + lrow) * LDB + kg + cgl * 8],
                         &Bs[chunk * 512]);
        }
        __syncthreads();
        bf16x8 af[4], bfr[4];
#pragma unroll
        for (int mt = 0; mt < 4; mt++) {
            int ar = wr * 64 + mt * 16 + l15;
            af[mt] = *(const bf16x8*)&As[(ar * 4 + qx) * 8];
        }
#pragma unroll
        for (int nt = 0; nt < 4; nt++) {
            int br = wc * 64 + nt * 16 + l15;
            bfr[nt] = *(const bf16x8*)&Bs[(br * 4 + qx) * 8];
        }
#pragma unroll
        for (int mt = 0; mt < 4; mt++)
#pragma unroll
            for (int nt = 0; nt < 4; nt++)
                acc[mt][nt] = __builtin_amdgcn_mfma_f32_16x16x32_bf16(
                    af[mt], bfr[nt], acc[mt][nt], 0, 0, 0);
        __syncthreads();
    }

#pragma unroll
    for (int mt = 0; mt < 4; mt++) {
#pragma unroll
        for (int nt = 0; nt < 4; nt++) {
            int n = n0 + wc * 64 + nt * 16 + l15;
#pragma unroll
            for (int r = 0; r < 4; r++) {
                int m = m0 + wr * 64 + mt * 16 + q * 4 + r;
                float* p = &C[(size_t)m * LDC + n];
                if (ATOMIC)
                    __hip_atomic_fetch_add(p, acc[mt][nt][r],
                                           __ATOMIC_RELAXED, __HIP_MEMORY_SCOPE_AGENT);
                else
                    *p = acc[mt][nt][r];
            }
        }
    }
}

// Distinct names so each shows separately in the profile.
__global__ __launch_bounds__(256) void k2_gemm(
    const unsigned short* __restrict__ A, const unsigned short* __restrict__ Bm,
    float* __restrict__ C, size_t sA, size_t sB, size_t sC)
{
    gemm_core<2048, 2048, 4096, 2048, 1, false>(A, Bm, C, sA, sB, sC);
}

__global__ __launch_bounds__(256) void k4_gemm(
    const unsigned short* __restrict__ A, const unsigned short* __restrict__ Bm,
    float* __restrict__ C, size_t sA, size_t sB, size_t sC)
{
    gemm_core<8192, 4096, 1024, 1024, 4, true>(A, Bm, C, sA, sB, sC);
}

// ---------------- K3: row softmax, fp32 sim -> bf16 P in place -------------
// blockIdx.x = global row; batch = row>>12 selects sim buffer via stride.
__global__ __launch_bounds__(256) void softmax_kernel(float* __restrict__ simbase,
                                                      size_t batchStride)
{
    const int row = blockIdx.x;
    float* sim = simbase + (size_t)(row >> 12) * batchStride;
    const int r = row & 4095;
    const float* pin = sim + (size_t)r * 4096;
    unsigned short* pout = (unsigned short*)sim + (size_t)r * 8192;
    const int tid = threadIdx.x;

    float v[16];
#pragma unroll
    for (int i = 0; i < 4; i++) {
        float4 d = ((const float4*)pin)[tid * 4 + i];
        v[4 * i + 0] = d.x * 0.03125f;
        v[4 * i + 1] = d.y * 0.03125f;
        v[4 * i + 2] = d.z * 0.03125f;
        v[4 * i + 3] = d.w * 0.03125f;
    }

    float m = v[0];
#pragma unroll
    for (int i = 1; i < 16; i++) m = fmaxf(m, v[i]);
    for (int o = 32; o > 0; o >>= 1) m = fmaxf(m, __shfl_xor(m, o));
    __shared__ float red[4];
    if ((tid & 63) == 0) red[tid >> 6] = m;
    __syncthreads();
    m = fmaxf(fmaxf(red[0], red[1]), fmaxf(red[2], red[3]));
    __syncthreads();

    float e[16];
    float s = 0.f;
#pragma unroll
    for (int i = 0; i < 16; i++) { e[i] = expf(v[i] - m); s += e[i]; }
    for (int o = 32; o > 0; o >>= 1) s += __shfl_xor(s, o);
    if ((tid & 63) == 0) red[tid >> 6] = s;
    __syncthreads();
    float l = (red[0] + red[1]) + (red[2] + red[3]);
    float inv = 1.0f / l;

#pragma unroll
    for (int c = 0; c < 2; c++) {
        unsigned int wds[4];
#pragma unroll
        for (int i = 0; i < 4; i++) {
            unsigned int lo = f2b(e[c * 8 + 2 * i] * inv);
            unsigned int hi = f2b(e[c * 8 + 2 * i + 1] * inv);
            wds[i] = lo | (hi << 16);
        }
        uint4 o4; o4.x = wds[0]; o4.y = wds[1]; o4.z = wds[2]; o4.w = wds[3];
        ((uint4*)pout)[tid * 2 + c] = o4;
    }
}

extern "C" void kernel_launch(void* const* d_in, const int* in_sizes, int n_in,
                              void* d_out, int out_size, void* d_ws, size_t ws_size,
                              hipStream_t stream)
{
    const float* x  = (const float*)d_in[0];
    const float* Wq = (const float*)d_in[1];
    const float* bq = (const float*)d_in[2];
    const float* Wk = (const float*)d_in[3];
    const float* bk = (const float*)d_in[4];
    const float* Wv = (const float*)d_in[5];
    const float* bv = (const float*)d_in[6];
    const float* ph = (const float*)d_in[7];

    char* ws = (char*)d_ws;
    const size_t SIMB = (size_t)4096 * 4096 * 4;                  // 67.1MB
    unsigned short* Xhi = (unsigned short*)ws;                    // aliases sim0
    unsigned short* Xlo = Xhi + (size_t)8192 * 1024;
    unsigned short* Whi = Xlo + (size_t)8192 * 1024;
    unsigned short* Wlo = Whi + (size_t)3072 * 1024;
    float*          sim0 = (float*)ws;
    unsigned short* Qf = (unsigned short*)(ws + SIMB);            // [2][4096][2048]
    unsigned short* Kf = Qf + (size_t)2 * 4096 * 2048;            // [2][4096][2048]
    unsigned short* Vt = Kf + (size_t)2 * 4096 * 2048;            // [2][1024][4096]
    float*          sim1 = (float*)(ws + SIMB + (size_t)83886080); // after Vt
    const bool twoSim = ws_size >= (size_t)218103808;

    hipMemsetAsync(d_out, 0, (size_t)2 * 4096 * 1024 * sizeof(float), stream);
    split_kernel<<<8192, 256, 0, stream>>>(x, Xhi, Xlo, 8192 * 1024 / 4);
    split_w_kernel<<<dim3(1024, 3), 256, 0, stream>>>(Wq, Wk, Wv, Whi, Wlo);
    proj_kernel<<<dim3(24, 64), 256, 0, stream>>>(Xhi, Xlo, Whi, Wlo,
                                                  bq, bk, bv, ph, Qf, Kf, Vt);

    const size_t sQK = (size_t)4096 * 2048;    // Qf/Kf batch stride (shorts)
    const size_t sV  = (size_t)1024 * 4096;    // Vt batch stride (shorts)
    const size_t sO  = (size_t)4096 * 1024;    // out batch stride (floats)

    if (twoSim) {
        const size_t sSim = (size_t)(sim1 - sim0);   // floats between sims
        k2_gemm<<<dim3(32, 32, 2), 256, 0, stream>>>(Qf, Kf, sim0, sQK, sQK, sSim);
        softmax_kernel<<<8192, 256, 0, stream>>>(sim0, sSim);
        k4_gemm<<<dim3(8, 32, 8), 256, 0, stream>>>((const unsigned short*)sim0, Vt,
                                                    (float*)d_out, sSim * 2, sV, sO);
    } else {
        for (int b = 0; b < 2; b++) {
            const unsigned short* Qb = Qf + (size_t)b * sQK;
            const unsigned short* Kb = Kf + (size_t)b * sQK;
            const unsigned short* Vb = Vt + (size_t)b * sV;
            float* outb = (float*)d_out + (size_t)b * sO;
            k2_gemm<<<dim3(32, 32, 1), 256, 0, stream>>>(Qb, Kb, sim0, 0, 0, 0);
            softmax_kernel<<<4096, 256, 0, stream>>>(sim0, 0);
            k4_gemm<<<dim3(8, 32, 4), 256, 0, stream>>>((const unsigned short*)sim0, Vb,
                                                        outb, 0, 0, 0);
        }
    }
}

// Round 9
// 618.939 us; speedup vs baseline: 1.1726x; 1.0774x over previous
//
#include <hip/hip_runtime.h>
#include <math.h>

// EulerAttention: B=2, S=4096, D=1024.
// Pipeline: [K0] split fp32 -> (hi,lo) bf16 for x and stacked W  (elementwise)
//           [K1] split-bf16 MFMA GEMM (3-term), M=8192 N=3072 K=1024,
//                epilogue: bias + HW-trig sincos -> Qf/Kf bf16 features, V -> Vt
//           [K2] bf16 MFMA NT GEMM (batches merged, z=2): sim(fp32) = Qf @ Kf^T
//           [K3] row softmax: fp32 sim -> bf16 P in place (row stride 8192)
//           [K4] bf16 MFMA NT GEMM split-K x2 -> separate fp32 partials
//                (aliasing Qf/Kf, dead after K2), then [K5] float4 reduce -> out
// ws (two-sim mode, 218MB): [sim0 67MB (aliases split bufs)][Qf 33.5][Kf 33.5]
//   [Vt 16.8][sim1 67]. Partials alias Qf+Kf after K2. Fallback <218MB:
//   sequential per-batch, atomic split-K k4 (R8 path).
//
// Precision notes (load-bearing):
//  - sim ~ 640 +- ~15 (cos(small)~1 common mode). sim MUST be fp32 (R1 failure).
//  - Q/K need near-fp32: inv_wl[0]~163 amplifies Q error. 3-term split-bf16.
//  - R3 failure: libm sincosf + reg pressure -> scratch spill -> 3.2GB phantom
//    writes. Trig MUST be inline v_sin/v_cos (revolutions, fract-reduced).
// Perf notes:
//  - R4: proj 186us = 831 TF (m97-structure plateau). Leave alone.
//  - R8: k2 at 648 TF, ZERO bank conflicts (R7 swizzle works), stall ~41%.
//    k4 at ~335 TF with 33.5M device-scope atomic adds -> R9 removes atomics
//    via separate partial buffers + reduce kernel (de-confounds atomic cost).

typedef __attribute__((ext_vector_type(8))) short bf16x8;
typedef __attribute__((ext_vector_type(4))) float f32x4;

__device__ __forceinline__ float b2f(unsigned short h) {
    union { unsigned int u; float f; } v; v.u = ((unsigned int)h) << 16; return v.f;
}
__device__ __forceinline__ unsigned short f2b(float f) {
    union { float f; unsigned int u; } v; v.f = f;
    unsigned int r = v.u + 0x7fffu + ((v.u >> 16) & 1u);
    return (unsigned short)(r >> 16);
}

// Async global->LDS 16B per lane. LDS dest = wave-uniform base + lane*16.
__device__ __forceinline__ void async_load16(const unsigned short* g, unsigned short* l) {
    __builtin_amdgcn_global_load_lds(
        (const __attribute__((address_space(1))) unsigned int*)g,
        (__attribute__((address_space(3))) unsigned int*)l, 16, 0, 0);
}

// Branch-free sin/cos of th (radians). HW v_sin/v_cos take REVOLUTIONS.
__device__ __forceinline__ void fast_sincos(float th, float* sn, float* cs) {
    float rev = th * 0.15915494309189535f;
    float fr  = rev - floorf(rev);
    float s, c;
    asm("v_sin_f32 %0, %1" : "=v"(s) : "v"(fr));
    asm("v_cos_f32 %0, %1" : "=v"(c) : "v"(fr));
    *sn = s; *cs = c;
}

// ---------------- K0: fp32 -> (hi, lo) bf16 split ----------------
__global__ __launch_bounds__(256) void split_kernel(
    const float* __restrict__ src,
    unsigned short* __restrict__ hi, unsigned short* __restrict__ lo, int n4)
{
    int i = blockIdx.x * 256 + threadIdx.x;
    if (i >= n4) return;
    float4 v = ((const float4*)src)[i];
    float f[4] = { v.x, v.y, v.z, v.w };
    unsigned short h[4], l[4];
#pragma unroll
    for (int j = 0; j < 4; j++) {
        h[j] = f2b(f[j]);
        float r = f[j] - b2f(h[j]);
        l[j] = f2b(r);
    }
    uint2 ho, lv;
    ho.x = (unsigned int)h[0] | ((unsigned int)h[1] << 16);
    ho.y = (unsigned int)h[2] | ((unsigned int)h[3] << 16);
    lv.x = (unsigned int)l[0] | ((unsigned int)l[1] << 16);
    lv.y = (unsigned int)l[2] | ((unsigned int)l[3] << 16);
    ((uint2*)hi)[i] = ho;
    ((uint2*)lo)[i] = lv;
}

__global__ __launch_bounds__(256) void split_w_kernel(
    const float* __restrict__ Wq, const float* __restrict__ Wk,
    const float* __restrict__ Wv,
    unsigned short* __restrict__ hi, unsigned short* __restrict__ lo)
{
    const int y = blockIdx.y;
    const float* src = (y == 0) ? Wq : ((y == 1) ? Wk : Wv);
    size_t off4 = (size_t)y * (1024 * 1024 / 4);
    int i = blockIdx.x * 256 + threadIdx.x;
    float4 v = ((const float4*)src)[i];
    float f[4] = { v.x, v.y, v.z, v.w };
    unsigned short h[4], l[4];
#pragma unroll
    for (int j = 0; j < 4; j++) {
        h[j] = f2b(f[j]);
        float r = f[j] - b2f(h[j]);
        l[j] = f2b(r);
    }
    uint2 ho, lv;
    ho.x = (unsigned int)h[0] | ((unsigned int)h[1] << 16);
    ho.y = (unsigned int)h[2] | ((unsigned int)h[3] << 16);
    lv.x = (unsigned int)l[0] | ((unsigned int)l[1] << 16);
    lv.y = (unsigned int)l[2] | ((unsigned int)l[3] << 16);
    ((uint2*)hi)[off4 + i] = ho;
    ((uint2*)lo)[off4 + i] = lv;
}

// ---------------- K1: split-bf16 MFMA projection GEMM ----------------
__global__ __launch_bounds__(256, 2) void proj_kernel(
    const unsigned short* __restrict__ Xhi, const unsigned short* __restrict__ Xlo,
    const unsigned short* __restrict__ Whi, const unsigned short* __restrict__ Wlo,
    const float* __restrict__ bq, const float* __restrict__ bk,
    const float* __restrict__ bv, const float* __restrict__ phase,
    unsigned short* __restrict__ Qf, unsigned short* __restrict__ Kf,
    unsigned short* __restrict__ Vt)
{
    const int m0 = blockIdx.y * 128;
    const int n0 = blockIdx.x * 128;

    __shared__ unsigned short Ah[128 * 40], Al[128 * 40];
    __shared__ unsigned short Bh[128 * 40], Bl[128 * 40];

    const int tid  = threadIdx.x;
    const int lane = tid & 63;
    const int w    = tid >> 6;
    const int wr   = w >> 1, wc = w & 1;
    const int l15  = lane & 15, q = lane >> 4;

    f32x4 acc[4][4];
#pragma unroll
    for (int a = 0; a < 4; a++)
#pragma unroll
        for (int b = 0; b < 4; b++) acc[a][b] = (f32x4){0.f, 0.f, 0.f, 0.f};

    for (int k0 = 0; k0 < 1024; k0 += 32) {
#pragma unroll
        for (int i = 0; i < 2; i++) {
            int idx = tid + 256 * i;
            int row = idx >> 2;
            int cc  = idx & 3;
            size_t ga = (size_t)(m0 + row) * 1024 + k0 + cc * 8;
            size_t gb = (size_t)(n0 + row) * 1024 + k0 + cc * 8;
            *(uint4*)&Ah[row * 40 + cc * 8] = *(const uint4*)&Xhi[ga];
            *(uint4*)&Al[row * 40 + cc * 8] = *(const uint4*)&Xlo[ga];
            *(uint4*)&Bh[row * 40 + cc * 8] = *(const uint4*)&Whi[gb];
            *(uint4*)&Bl[row * 40 + cc * 8] = *(const uint4*)&Wlo[gb];
        }
        __syncthreads();
        bf16x8 ah[4], al[4];
#pragma unroll
        for (int mt = 0; mt < 4; mt++) {
            int off = (wr * 64 + mt * 16 + l15) * 40 + q * 8;
            ah[mt] = *(const bf16x8*)&Ah[off];
            al[mt] = *(const bf16x8*)&Al[off];
        }
#pragma unroll
        for (int nt = 0; nt < 4; nt++) {
            int off = (wc * 64 + nt * 16 + l15) * 40 + q * 8;
            bf16x8 bh = *(const bf16x8*)&Bh[off];
            bf16x8 bl = *(const bf16x8*)&Bl[off];
#pragma unroll
            for (int mt = 0; mt < 4; mt++) {
                acc[mt][nt] = __builtin_amdgcn_mfma_f32_16x16x32_bf16(
                    ah[mt], bh, acc[mt][nt], 0, 0, 0);
                acc[mt][nt] = __builtin_amdgcn_mfma_f32_16x16x32_bf16(
                    ah[mt], bl, acc[mt][nt], 0, 0, 0);
                acc[mt][nt] = __builtin_amdgcn_mfma_f32_16x16x32_bf16(
                    al[mt], bh, acc[mt][nt], 0, 0, 0);
            }
        }
        __syncthreads();
    }

    const int z = n0 >> 10;                   // 0=Q, 1=K, 2=V
    const float* bias = (z == 0) ? bq : ((z == 1) ? bk : bv);
    const float w0 = (float)(2.0 * M_PI / 1024.0);

#pragma unroll
    for (int mt = 0; mt < 4; mt++) {
#pragma unroll
        for (int nt = 0; nt < 4; nt++) {
            int n = n0 + wc * 64 + nt * 16 + l15;
            int f = n & 1023;
            float bsv = bias[f];
            float wl  = (float)(f + 1) * w0;
            float inv = 1.0f / (wl + 1e-8f);
            float phv = phase[f];
#pragma unroll
            for (int r = 0; r < 4; r++) {
                int m  = m0 + wr * 64 + mt * 16 + q * 4 + r;
                int bb = m >> 12;
                int s  = m & 4095;
                float val = acc[mt][nt][r] + bsv;
                if (z == 2) {
                    Vt[((size_t)bb * 1024 + f) * 4096 + s] = f2b(val);
                } else {
                    float th = fmaf(val, inv, phv);
                    float sn, cs;
                    fast_sincos(th, &sn, &cs);
                    unsigned short* dst = (z == 0) ? Qf : Kf;
                    size_t base = ((size_t)bb * 4096 + s) * 2048;
                    dst[base + f]        = f2b(cs);
                    dst[base + 1024 + f] = f2b(sn);
                }
            }
        }
    }
}

// ---------------- K2/K4 core: bf16 MFMA NT GEMM, compile-time strides ------
// C[m][n] (+)= sum_{k in slice} A[m][k]*Bm[n][k]. 128x128 tile, BK=32,
// 4 waves 2x2, mfma_f32_16x16x32_bf16 4x4/wave. Swizzled global_load_lds
// (width=16): lane i fetches global chunk (i&3)^((i>>3)&3); fragment (row,q)
// at 16B-slot row*4+(q^((row>>1)&3)) -> 2-way banks (free; verified R8:
// SQ_LDS_BANK_CONFLICT=0).
// blockIdx.z = batch*SLICES + slice. PARTIAL: C += z*sC (separate per-slice
// outputs, plain stores). ATOMIC: C += batch*sC, device-scope atomic adds.
template <int LDA, int LDB, int LDC, int KLEN, int SLICES, bool ATOMIC, bool PARTIAL>
__device__ __forceinline__ void gemm_core(
    const unsigned short* __restrict__ A,
    const unsigned short* __restrict__ Bm,
    float* __restrict__ C, size_t sA, size_t sB, size_t sC)
{
    const int bz = blockIdx.z;
    const int batch = bz / SLICES;
    const int slice = bz % SLICES;
    A  += (size_t)batch * sA;
    Bm += (size_t)batch * sB;
    C  += PARTIAL ? (size_t)bz * sC : (size_t)batch * sC;
    const int koff = slice * KLEN;

    const int m0 = blockIdx.y * 128;
    const int n0 = blockIdx.x * 128;

    __shared__ unsigned short As[128 * 32];
    __shared__ unsigned short Bs[128 * 32];

    const int tid  = threadIdx.x;
    const int lane = tid & 63;
    const int w    = tid >> 6;
    const int wr   = w >> 1, wc = w & 1;
    const int l15  = lane & 15, q = lane >> 4;
    const int lrow = lane >> 2;
    const int cgl  = (lane & 3) ^ ((lane >> 3) & 3);
    const int qx   = q ^ ((l15 >> 1) & 3);

    f32x4 acc[4][4];
#pragma unroll
    for (int a = 0; a < 4; a++)
#pragma unroll
        for (int b = 0; b < 4; b++) acc[a][b] = (f32x4){0.f, 0.f, 0.f, 0.f};

    for (int k0 = 0; k0 < KLEN; k0 += 32) {
        int kg = koff + k0;
#pragma unroll
        for (int i = 0; i < 2; i++) {
            int chunk = w * 2 + i;
            async_load16(&A[(size_t)(m0 + chunk * 16 + lrow) * LDA + kg + cgl * 8],
                         &As[chunk * 512]);
            async_load16(&Bm[(size_t)(n0 + chunk * 16 + lrow) * LDB + kg + cgl * 8],
                         &Bs[chunk * 512]);
        }
        __syncthreads();
        bf16x8 af[4], bfr[4];
#pragma unroll
        for (int mt = 0; mt < 4; mt++) {
            int ar = wr * 64 + mt * 16 + l15;
            af[mt] = *(const bf16x8*)&As[(ar * 4 + qx) * 8];
        }
#pragma unroll
        for (int nt = 0; nt < 4; nt++) {
            int br = wc * 64 + nt * 16 + l15;
            bfr[nt] = *(const bf16x8*)&Bs[(br * 4 + qx) * 8];
        }
#pragma unroll
        for (int mt = 0; mt < 4; mt++)
#pragma unroll
            for (int nt = 0; nt < 4; nt++)
                acc[mt][nt] = __builtin_amdgcn_mfma_f32_16x16x32_bf16(
                    af[mt], bfr[nt], acc[mt][nt], 0, 0, 0);
        __syncthreads();
    }

#pragma unroll
    for (int mt = 0; mt < 4; mt++) {
#pragma unroll
        for (int nt = 0; nt < 4; nt++) {
            int n = n0 + wc * 64 + nt * 16 + l15;
#pragma unroll
            for (int r = 0; r < 4; r++) {
                int m = m0 + wr * 64 + mt * 16 + q * 4 + r;
                float* p = &C[(size_t)m * LDC + n];
                if (ATOMIC)
                    __hip_atomic_fetch_add(p, acc[mt][nt][r],
                                           __ATOMIC_RELAXED, __HIP_MEMORY_SCOPE_AGENT);
                else
                    *p = acc[mt][nt][r];
            }
        }
    }
}

__global__ __launch_bounds__(256) void k2_gemm(
    const unsigned short* __restrict__ A, const unsigned short* __restrict__ Bm,
    float* __restrict__ C, size_t sA, size_t sB, size_t sC)
{
    gemm_core<2048, 2048, 4096, 2048, 1, false, false>(A, Bm, C, sA, sB, sC);
}

// k4 two-sim path: split-K x2, separate partial buffers (plain stores).
__global__ __launch_bounds__(256) void k4_gemm(
    const unsigned short* __restrict__ A, const unsigned short* __restrict__ Bm,
    float* __restrict__ C, size_t sA, size_t sB, size_t sC)
{
    gemm_core<8192, 4096, 1024, 2048, 2, false, true>(A, Bm, C, sA, sB, sC);
}

// k4 fallback path (one sim): atomic split-K x4 within one batch.
__global__ __launch_bounds__(256) void k4_gemm_atomic(
    const unsigned short* __restrict__ A, const unsigned short* __restrict__ Bm,
    float* __restrict__ C, size_t sA, size_t sB, size_t sC)
{
    gemm_core<8192, 4096, 1024, 1024, 4, true, false>(A, Bm, C, sA, sB, sC);
}

// ---------------- K5: reduce partials -> out ----------------
// part layout: [batch*2 + slice][4096*1024] fp32. out[j] = p0[j] + p1[j].
__global__ __launch_bounds__(256) void reduce_kernel(
    const float* __restrict__ part, float* __restrict__ out)
{
    int j4 = blockIdx.x * 256 + threadIdx.x;      // float4 index, < 2*1048576
    int b  = j4 >> 20;
    int jj = j4 & 1048575;
    const float4* p0 = (const float4*)(part + (size_t)(b * 2 + 0) * 4194304);
    const float4* p1 = (const float4*)(part + (size_t)(b * 2 + 1) * 4194304);
    float4 a = p0[jj], c = p1[jj];
    float4 r; r.x = a.x + c.x; r.y = a.y + c.y; r.z = a.z + c.z; r.w = a.w + c.w;
    ((float4*)out)[j4] = r;
}

// ---------------- K3: row softmax, fp32 sim -> bf16 P in place -------------
__global__ __launch_bounds__(256) void softmax_kernel(float* __restrict__ simbase,
                                                      size_t batchStride)
{
    const int row = blockIdx.x;
    float* sim = simbase + (size_t)(row >> 12) * batchStride;
    const int r = row & 4095;
    const float* pin = sim + (size_t)r * 4096;
    unsigned short* pout = (unsigned short*)sim + (size_t)r * 8192;
    const int tid = threadIdx.x;

    float v[16];
#pragma unroll
    for (int i = 0; i < 4; i++) {
        float4 d = ((const float4*)pin)[tid * 4 + i];
        v[4 * i + 0] = d.x * 0.03125f;
        v[4 * i + 1] = d.y * 0.03125f;
        v[4 * i + 2] = d.z * 0.03125f;
        v[4 * i + 3] = d.w * 0.03125f;
    }

    float m = v[0];
#pragma unroll
    for (int i = 1; i < 16; i++) m = fmaxf(m, v[i]);
    for (int o = 32; o > 0; o >>= 1) m = fmaxf(m, __shfl_xor(m, o));
    __shared__ float red[4];
    if ((tid & 63) == 0) red[tid >> 6] = m;
    __syncthreads();
    m = fmaxf(fmaxf(red[0], red[1]), fmaxf(red[2], red[3]));
    __syncthreads();

    float e[16];
    float s = 0.f;
#pragma unroll
    for (int i = 0; i < 16; i++) { e[i] = expf(v[i] - m); s += e[i]; }
    for (int o = 32; o > 0; o >>= 1) s += __shfl_xor(s, o);
    if ((tid & 63) == 0) red[tid >> 6] = s;
    __syncthreads();
    float l = (red[0] + red[1]) + (red[2] + red[3]);
    float inv = 1.0f / l;

#pragma unroll
    for (int c = 0; c < 2; c++) {
        unsigned int wds[4];
#pragma unroll
        for (int i = 0; i < 4; i++) {
            unsigned int lo = f2b(e[c * 8 + 2 * i] * inv);
            unsigned int hi = f2b(e[c * 8 + 2 * i + 1] * inv);
            wds[i] = lo | (hi << 16);
        }
        uint4 o4; o4.x = wds[0]; o4.y = wds[1]; o4.z = wds[2]; o4.w = wds[3];
        ((uint4*)pout)[tid * 2 + c] = o4;
    }
}

extern "C" void kernel_launch(void* const* d_in, const int* in_sizes, int n_in,
                              void* d_out, int out_size, void* d_ws, size_t ws_size,
                              hipStream_t stream)
{
    const float* x  = (const float*)d_in[0];
    const float* Wq = (const float*)d_in[1];
    const float* bq = (const float*)d_in[2];
    const float* Wk = (const float*)d_in[3];
    const float* bk = (const float*)d_in[4];
    const float* Wv = (const float*)d_in[5];
    const float* bv = (const float*)d_in[6];
    const float* ph = (const float*)d_in[7];

    char* ws = (char*)d_ws;
    const size_t SIMB = (size_t)4096 * 4096 * 4;                  // 67.1MB
    unsigned short* Xhi = (unsigned short*)ws;                    // aliases sim0
    unsigned short* Xlo = Xhi + (size_t)8192 * 1024;
    unsigned short* Whi = Xlo + (size_t)8192 * 1024;
    unsigned short* Wlo = Whi + (size_t)3072 * 1024;
    float*          sim0 = (float*)ws;
    unsigned short* Qf = (unsigned short*)(ws + SIMB);            // [2][4096][2048]
    unsigned short* Kf = Qf + (size_t)2 * 4096 * 2048;            // [2][4096][2048]
    unsigned short* Vt = Kf + (size_t)2 * 4096 * 2048;            // [2][1024][4096]
    float*          sim1 = (float*)(ws + SIMB + (size_t)83886080); // after Vt
    float*          part = (float*)(ws + SIMB);                   // aliases Qf+Kf (dead after k2)
    const bool twoSim = ws_size >= (size_t)218103808;

    split_kernel<<<8192, 256, 0, stream>>>(x, Xhi, Xlo, 8192 * 1024 / 4);
    split_w_kernel<<<dim3(1024, 3), 256, 0, stream>>>(Wq, Wk, Wv, Whi, Wlo);
    proj_kernel<<<dim3(24, 64), 256, 0, stream>>>(Xhi, Xlo, Whi, Wlo,
                                                  bq, bk, bv, ph, Qf, Kf, Vt);

    const size_t sQK = (size_t)4096 * 2048;    // Qf/Kf batch stride (shorts)
    const size_t sV  = (size_t)1024 * 4096;    // Vt batch stride (shorts)
    const size_t sO  = (size_t)4096 * 1024;    // out / partial stride (floats)

    if (twoSim) {
        const size_t sSim = (size_t)(sim1 - sim0);   // floats between sims
        k2_gemm<<<dim3(32, 32, 2), 256, 0, stream>>>(Qf, Kf, sim0, sQK, sQK, sSim);
        softmax_kernel<<<8192, 256, 0, stream>>>(sim0, sSim);
        // out partials: z = batch*2 + slice, each slice K=2048 of 4096
        k4_gemm<<<dim3(8, 32, 4), 256, 0, stream>>>((const unsigned short*)sim0, Vt,
                                                    part, sSim * 2, sV, sO);
        reduce_kernel<<<8192, 256, 0, stream>>>(part, (float*)d_out);
    } else {
        hipMemsetAsync(d_out, 0, (size_t)2 * 4096 * 1024 * sizeof(float), stream);
        for (int b = 0; b < 2; b++) {
            const unsigned short* Qb = Qf + (size_t)b * sQK;
            const unsigned short* Kb = Kf + (size_t)b * sQK;
            const unsigned short* Vb = Vt + (size_t)b * sV;
            float* outb = (float*)d_out + (size_t)b * sO;
            k2_gemm<<<dim3(32, 32, 1), 256, 0, stream>>>(Qb, Kb, sim0, 0, 0, 0);
            softmax_kernel<<<4096, 256, 0, stream>>>(sim0, 0);
            k4_gemm_atomic<<<dim3(8, 32, 4), 256, 0, stream>>>(
                (const unsigned short*)sim0, Vb, outb, 0, 0, 0);
        }
    }
}